// Round 1
// baseline (405.096 us; speedup 1.0000x reference)
//
#include <hip/hip_runtime.h>
#include <math.h>

#define N_NODES 10000
#define FDIM 256
#define NEG_SLOPE 0.2f

// ---------------- CSR build ----------------

__global__ void hist_dst(const int* __restrict__ pos_ei, int* __restrict__ cnt,
                         int E_pos, int E_tot) {
    int e = blockIdx.x * blockDim.x + threadIdx.x;
    if (e < E_tot) {
        int d = (e < E_pos) ? pos_ei[E_pos + e] : (e - E_pos);
        atomicAdd(&cnt[d], 1);
    }
}

__global__ __launch_bounds__(1024) void scan10k(const int* __restrict__ cnt,
                                                int* __restrict__ row_ptr,
                                                int* __restrict__ fill, int N) {
    const int CH = 10;  // 1024*10 >= 10000
    __shared__ int sums[1024];
    int tid = threadIdx.x;
    int base = tid * CH;
    int vals[CH];
    int s = 0;
#pragma unroll
    for (int i = 0; i < CH; ++i) {
        int idx = base + i;
        int v = (idx < N) ? cnt[idx] : 0;
        vals[i] = s;   // exclusive within thread
        s += v;
    }
    sums[tid] = s;
    __syncthreads();
    // Hillis-Steele inclusive scan (read phase / barrier / write phase / barrier)
    for (int off = 1; off < 1024; off <<= 1) {
        int v = (tid >= off) ? sums[tid - off] : 0;
        __syncthreads();
        sums[tid] += v;
        __syncthreads();
    }
    int toff = (tid == 0) ? 0 : sums[tid - 1];
#pragma unroll
    for (int i = 0; i < CH; ++i) {
        int idx = base + i;
        if (idx < N) {
            int rp = toff + vals[i];
            row_ptr[idx] = rp;
            fill[idx] = rp;
        }
    }
    if (tid == 0) row_ptr[N] = sums[1023];
}

__global__ void scatter_edges(const int* __restrict__ pos_ei, int* __restrict__ fill,
                              int* __restrict__ srcs, int E_pos, int E_tot) {
    int e = blockIdx.x * blockDim.x + threadIdx.x;
    if (e < E_tot) {
        int s, d;
        if (e < E_pos) { s = pos_ei[e]; d = pos_ei[E_pos + e]; }
        else           { s = e - E_pos; d = s; }
        int pos = atomicAdd(&fill[d], 1);
        srcs[pos] = s;
    }
}

// ---------------- fp32 GEMM: C[M,256] = A[M,256] @ B[256,256] (+bias) -------

__global__ __launch_bounds__(256) void gemm256(const float* __restrict__ A,
                                               const float* __restrict__ B,
                                               const float* __restrict__ bias,
                                               float* __restrict__ C,
                                               int M, int has_bias) {
    const int K = FDIM;
    __shared__ float As[16][68];
    __shared__ float Bs[16][68];
    int tid = threadIdx.x;
    int tx = tid & 15, ty = tid >> 4;
    int mBase = blockIdx.x * 64;
    int nBase = blockIdx.y * 64;
    float acc[4][4] = {};
    int lm = tid >> 2, lk = (tid & 3) * 4;   // A staging coords
    int bk = tid >> 4, bn = (tid & 15) * 4;  // B staging coords

    for (int k0 = 0; k0 < K; k0 += 16) {
        float4 a4 = make_float4(0.f, 0.f, 0.f, 0.f);
        int row = mBase + lm;
        if (row < M) a4 = *(const float4*)(A + row * K + k0 + lk);
        float4 b4 = *(const float4*)(B + (k0 + bk) * FDIM + nBase + bn);
        __syncthreads();  // prev-iter LDS reads done before overwrite
        As[lk + 0][lm] = a4.x;
        As[lk + 1][lm] = a4.y;
        As[lk + 2][lm] = a4.z;
        As[lk + 3][lm] = a4.w;
        *(float4*)&Bs[bk][bn] = b4;
        __syncthreads();
#pragma unroll
        for (int kk = 0; kk < 16; ++kk) {
            float4 av = *(const float4*)&As[kk][ty * 4];
            float4 bv = *(const float4*)&Bs[kk][tx * 4];
            float a[4] = {av.x, av.y, av.z, av.w};
            float b[4] = {bv.x, bv.y, bv.z, bv.w};
#pragma unroll
            for (int i = 0; i < 4; ++i)
#pragma unroll
                for (int j = 0; j < 4; ++j)
                    acc[i][j] = fmaf(a[i], b[j], acc[i][j]);
        }
    }
#pragma unroll
    for (int i = 0; i < 4; ++i) {
        int row = mBase + ty * 4 + i;
        if (row >= M) continue;
        int col = nBase + tx * 4;
        float4 o = make_float4(acc[i][0], acc[i][1], acc[i][2], acc[i][3]);
        if (has_bias) {
            o.x += bias[col + 0];
            o.y += bias[col + 1];
            o.z += bias[col + 2];
            o.w += bias[col + 3];
        }
        *(float4*)(C + row * FDIM + col) = o;
    }
}

// -------- attention logits: al_s[i] = t[i,:]@a_src, al_d[i] = t[i,:]@a_dst --

__global__ __launch_bounds__(256) void attn_logits(const float* __restrict__ t,
                                                   const float* __restrict__ a_src,
                                                   const float* __restrict__ a_dst,
                                                   float* __restrict__ al_s,
                                                   float* __restrict__ al_d) {
    int node = blockIdx.x;
    int tidx = threadIdx.x;
    float v = t[node * FDIM + tidx];
    float ps = v * a_src[tidx];
    float pd = v * a_dst[tidx];
    for (int o = 32; o; o >>= 1) {
        ps += __shfl_down(ps, o);
        pd += __shfl_down(pd, o);
    }
    __shared__ float ss[4], sd[4];
    int w = tidx >> 6, lane = tidx & 63;
    if (lane == 0) { ss[w] = ps; sd[w] = pd; }
    __syncthreads();
    if (tidx == 0) {
        al_s[node] = ss[0] + ss[1] + ss[2] + ss[3];
        al_d[node] = sd[0] + sd[1] + sd[2] + sd[3];
    }
}

// -------- per-destination-node edge softmax (one wave per node) ------------

__global__ __launch_bounds__(256) void edge_softmax(const float* __restrict__ al_s,
                                                    const float* __restrict__ al_d,
                                                    const int* __restrict__ row_ptr,
                                                    const int* __restrict__ srcs,
                                                    float* __restrict__ alpha, int N) {
    int wave = threadIdx.x >> 6;
    int lane = threadIdx.x & 63;
    int node = blockIdx.x * 4 + wave;
    if (node >= N) return;
    int beg = row_ptr[node], end = row_ptr[node + 1];
    float ad = al_d[node];
    float m = -INFINITY;
    for (int j = beg + lane; j < end; j += 64) {
        float e = al_s[srcs[j]] + ad;
        e = (e > 0.f) ? e : NEG_SLOPE * e;
        m = fmaxf(m, e);
    }
    for (int o = 32; o; o >>= 1) m = fmaxf(m, __shfl_down(m, o));
    m = __shfl(m, 0);
    float s = 0.f;
    for (int j = beg + lane; j < end; j += 64) {
        float e = al_s[srcs[j]] + ad;
        e = (e > 0.f) ? e : NEG_SLOPE * e;
        float ex = __expf(e - m);
        alpha[j] = ex;
        s += ex;
    }
    for (int o = 32; o; o >>= 1) s += __shfl_down(s, o);
    s = __shfl(s, 0);
    float inv = 1.f / (s + 1e-16f);
    for (int j = beg + lane; j < end; j += 64) alpha[j] *= inv;
}

// -------- aggregation: out[i,f] = bias[f] + sum_j alpha_j * t[src_j, f] ----

__global__ __launch_bounds__(256) void aggregate(const float* __restrict__ t,
                                                 const float* __restrict__ alpha,
                                                 const int* __restrict__ row_ptr,
                                                 const int* __restrict__ srcs,
                                                 const float* __restrict__ bias,
                                                 float* __restrict__ out) {
    int node = blockIdx.x;
    int f = threadIdx.x;
    int beg = row_ptr[node], end = row_ptr[node + 1];
    float acc = bias[f];
    for (int j = beg; j < end; ++j) {
        float a = alpha[j];
        int sj = srcs[j];
        acc = fmaf(a, t[sj * FDIM + f], acc);
    }
    out[node * FDIM + f] = acc;
}

// -------- logits: out[e] = dot(h[u], h[v]) ---------------------------------

__global__ __launch_bounds__(256) void edge_dot(const float* __restrict__ h,
                                                const int* __restrict__ ei,
                                                float* __restrict__ out, int EQ) {
    int w = threadIdx.x >> 6, lane = threadIdx.x & 63;
    int e = blockIdx.x * 4 + w;
    if (e >= EQ) return;
    int u = ei[e], v = ei[EQ + e];
    const float4* hu = (const float4*)(h + (size_t)u * FDIM);
    const float4* hv = (const float4*)(h + (size_t)v * FDIM);
    float4 a = hu[lane], b = hv[lane];
    float s = a.x * b.x + a.y * b.y + a.z * b.z + a.w * b.w;
    for (int o = 32; o; o >>= 1) s += __shfl_down(s, o);
    if (lane == 0) out[e] = s;
}

// ---------------------------------------------------------------------------

extern "C" void kernel_launch(void* const* d_in, const int* in_sizes, int n_in,
                              void* d_out, int out_size, void* d_ws, size_t ws_size,
                              hipStream_t stream) {
    const float* x       = (const float*)d_in[0];
    const int*   pos_ei  = (const int*)d_in[1];
    const int*   q_ei    = (const int*)d_in[2];
    const float* Win_W   = (const float*)d_in[3];
    const float* Win_b   = (const float*)d_in[4];
    const float* W1      = (const float*)d_in[5];
    const float* a1_src  = (const float*)d_in[6];
    const float* a1_dst  = (const float*)d_in[7];
    const float* b1      = (const float*)d_in[8];
    const float* W2      = (const float*)d_in[9];
    const float* a2_src  = (const float*)d_in[10];
    const float* a2_dst  = (const float*)d_in[11];
    const float* b2      = (const float*)d_in[12];
    float* logits = (float*)d_out;

    const int N = in_sizes[0] / FDIM;         // 10000
    const int E_pos = in_sizes[1] / 2;        // 320000
    const int EQ = in_sizes[2] / 2;           // 100000
    const int E_tot = E_pos + N;              // 330000

    // workspace carve-up (floats, then ints)
    float* h    = (float*)d_ws;               // N*FDIM
    float* t    = h + (size_t)N * FDIM;       // N*FDIM
    float* o2   = t + (size_t)N * FDIM;       // N*FDIM
    float* al_s = o2 + (size_t)N * FDIM;      // N
    float* al_d = al_s + N;                   // N
    float* alpha = al_d + N;                  // E_tot
    int* row_ptr = (int*)(alpha + E_tot);     // N+1
    int* fill    = row_ptr + (N + 1);         // N
    int* srcs    = fill + N;                  // E_tot
    int* cnt     = srcs + E_tot;              // N

    // ---- CSR build ----
    hipMemsetAsync(cnt, 0, (size_t)N * sizeof(int), stream);
    {
        int nb = (E_tot + 255) / 256;
        hist_dst<<<nb, 256, 0, stream>>>(pos_ei, cnt, E_pos, E_tot);
    }
    scan10k<<<1, 1024, 0, stream>>>(cnt, row_ptr, fill, N);
    {
        int nb = (E_tot + 255) / 256;
        scatter_edges<<<nb, 256, 0, stream>>>(pos_ei, fill, srcs, E_pos, E_tot);
    }

    dim3 ggrid((N + 63) / 64, FDIM / 64);

    // ---- input weighting: h = x @ Win_W + Win_b ----
    gemm256<<<ggrid, 256, 0, stream>>>(x, Win_W, Win_b, h, N, 1);

    // ---- GAT layer 1: h -> o2 ----
    gemm256<<<ggrid, 256, 0, stream>>>(h, W1, nullptr, t, N, 0);
    attn_logits<<<N, 256, 0, stream>>>(t, a1_src, a1_dst, al_s, al_d);
    edge_softmax<<<(N + 3) / 4, 256, 0, stream>>>(al_s, al_d, row_ptr, srcs, alpha, N);
    aggregate<<<N, 256, 0, stream>>>(t, alpha, row_ptr, srcs, b1, o2);

    // ---- GAT layer 2: o2 -> h ----
    gemm256<<<ggrid, 256, 0, stream>>>(o2, W2, nullptr, t, N, 0);
    attn_logits<<<N, 256, 0, stream>>>(t, a2_src, a2_dst, al_s, al_d);
    edge_softmax<<<(N + 3) / 4, 256, 0, stream>>>(al_s, al_d, row_ptr, srcs, alpha, N);
    aggregate<<<N, 256, 0, stream>>>(t, alpha, row_ptr, srcs, b2, h);

    // ---- logits ----
    edge_dot<<<(EQ + 3) / 4, 256, 0, stream>>>(h, q_ei, logits, EQ);
}

// Round 2
// 336.831 us; speedup vs baseline: 1.2027x; 1.2027x over previous
//
#include <hip/hip_runtime.h>
#include <math.h>

#define N_NODES 10000
#define FDIM 256
#define NEG_SLOPE 0.2f

// ---------------- CSR build ----------------

__global__ void hist_dst(const int* __restrict__ pos_ei, int* __restrict__ cnt,
                         int E_pos, int E_tot) {
    int e = blockIdx.x * blockDim.x + threadIdx.x;
    if (e < E_tot) {
        int d = (e < E_pos) ? pos_ei[E_pos + e] : (e - E_pos);
        atomicAdd(&cnt[d], 1);
    }
}

__global__ __launch_bounds__(1024) void scan10k(const int* __restrict__ cnt,
                                                int* __restrict__ row_ptr,
                                                int* __restrict__ fill, int N) {
    const int CH = 10;  // 1024*10 >= 10000
    __shared__ int sums[1024];
    int tid = threadIdx.x;
    int base = tid * CH;
    int vals[CH];
    int s = 0;
#pragma unroll
    for (int i = 0; i < CH; ++i) {
        int idx = base + i;
        int v = (idx < N) ? cnt[idx] : 0;
        vals[i] = s;   // exclusive within thread
        s += v;
    }
    sums[tid] = s;
    __syncthreads();
    for (int off = 1; off < 1024; off <<= 1) {
        int v = (tid >= off) ? sums[tid - off] : 0;
        __syncthreads();
        sums[tid] += v;
        __syncthreads();
    }
    int toff = (tid == 0) ? 0 : sums[tid - 1];
#pragma unroll
    for (int i = 0; i < CH; ++i) {
        int idx = base + i;
        if (idx < N) {
            int rp = toff + vals[i];
            row_ptr[idx] = rp;
            fill[idx] = rp;
        }
    }
    if (tid == 0) row_ptr[N] = sums[1023];
}

__global__ void scatter_edges(const int* __restrict__ pos_ei, int* __restrict__ fill,
                              int* __restrict__ srcs, int E_pos, int E_tot) {
    int e = blockIdx.x * blockDim.x + threadIdx.x;
    if (e < E_tot) {
        int s, d;
        if (e < E_pos) { s = pos_ei[e]; d = pos_ei[E_pos + e]; }
        else           { s = e - E_pos; d = s; }
        int pos = atomicAdd(&fill[d], 1);
        srcs[pos] = s;
    }
}

// ---------------- fp32 GEMM: C[M,256] = A[M,256] @ B[256,256] (+bias) -------

__global__ __launch_bounds__(256) void gemm256(const float* __restrict__ A,
                                               const float* __restrict__ B,
                                               const float* __restrict__ bias,
                                               float* __restrict__ C,
                                               int M, int has_bias) {
    const int K = FDIM;
    __shared__ float As[16][68];
    __shared__ float Bs[16][68];
    int tid = threadIdx.x;
    int tx = tid & 15, ty = tid >> 4;
    int mBase = blockIdx.x * 64;
    int nBase = blockIdx.y * 64;
    float acc[4][4] = {};
    int lm = tid >> 2, lk = (tid & 3) * 4;   // A staging coords
    int bk = tid >> 4, bn = (tid & 15) * 4;  // B staging coords

    for (int k0 = 0; k0 < K; k0 += 16) {
        float4 a4 = make_float4(0.f, 0.f, 0.f, 0.f);
        int row = mBase + lm;
        if (row < M) a4 = *(const float4*)(A + row * K + k0 + lk);
        float4 b4 = *(const float4*)(B + (k0 + bk) * FDIM + nBase + bn);
        __syncthreads();  // prev-iter LDS reads done before overwrite
        As[lk + 0][lm] = a4.x;
        As[lk + 1][lm] = a4.y;
        As[lk + 2][lm] = a4.z;
        As[lk + 3][lm] = a4.w;
        *(float4*)&Bs[bk][bn] = b4;
        __syncthreads();
#pragma unroll
        for (int kk = 0; kk < 16; ++kk) {
            float4 av = *(const float4*)&As[kk][ty * 4];
            float4 bv = *(const float4*)&Bs[kk][tx * 4];
            float a[4] = {av.x, av.y, av.z, av.w};
            float b[4] = {bv.x, bv.y, bv.z, bv.w};
#pragma unroll
            for (int i = 0; i < 4; ++i)
#pragma unroll
                for (int j = 0; j < 4; ++j)
                    acc[i][j] = fmaf(a[i], b[j], acc[i][j]);
        }
    }
#pragma unroll
    for (int i = 0; i < 4; ++i) {
        int row = mBase + ty * 4 + i;
        if (row >= M) continue;
        int col = nBase + tx * 4;
        float4 o = make_float4(acc[i][0], acc[i][1], acc[i][2], acc[i][3]);
        if (has_bias) {
            o.x += bias[col + 0];
            o.y += bias[col + 1];
            o.z += bias[col + 2];
            o.w += bias[col + 3];
        }
        *(float4*)(C + row * FDIM + col) = o;
    }
}

// -------- attention logits: al_s[i] = t[i,:]@a_src, al_d[i] = t[i,:]@a_dst --
// wave per node, float4 per lane

__global__ __launch_bounds__(256) void attn_logits(const float* __restrict__ t,
                                                   const float* __restrict__ a_src,
                                                   const float* __restrict__ a_dst,
                                                   float* __restrict__ al_s,
                                                   float* __restrict__ al_d, int N) {
    int w = threadIdx.x >> 6, lane = threadIdx.x & 63;
    int node = blockIdx.x * 4 + w;
    if (node >= N) return;
    float4 v = ((const float4*)t)[node * 64 + lane];
    float4 as = ((const float4*)a_src)[lane];
    float4 ad = ((const float4*)a_dst)[lane];
    float ps = v.x * as.x + v.y * as.y + v.z * as.z + v.w * as.w;
    float pd = v.x * ad.x + v.y * ad.y + v.z * ad.z + v.w * ad.w;
    for (int o = 32; o; o >>= 1) {
        ps += __shfl_down(ps, o);
        pd += __shfl_down(pd, o);
    }
    if (lane == 0) { al_s[node] = ps; al_d[node] = pd; }
}

// -------- per-destination-node edge softmax (one wave per node) ------------

__global__ __launch_bounds__(256) void edge_softmax(const float* __restrict__ al_s,
                                                    const float* __restrict__ al_d,
                                                    const int* __restrict__ row_ptr,
                                                    const int* __restrict__ srcs,
                                                    float* __restrict__ alpha, int N) {
    int wave = threadIdx.x >> 6;
    int lane = threadIdx.x & 63;
    int node = blockIdx.x * 4 + wave;
    if (node >= N) return;
    int beg = row_ptr[node], end = row_ptr[node + 1];
    float ad = al_d[node];
    float m = -INFINITY;
    for (int j = beg + lane; j < end; j += 64) {
        float e = al_s[srcs[j]] + ad;
        e = (e > 0.f) ? e : NEG_SLOPE * e;
        m = fmaxf(m, e);
    }
    for (int o = 32; o; o >>= 1) m = fmaxf(m, __shfl_down(m, o));
    m = __shfl(m, 0);
    float s = 0.f;
    for (int j = beg + lane; j < end; j += 64) {
        float e = al_s[srcs[j]] + ad;
        e = (e > 0.f) ? e : NEG_SLOPE * e;
        float ex = __expf(e - m);
        alpha[j] = ex;
        s += ex;
    }
    for (int o = 32; o; o >>= 1) s += __shfl_down(s, o);
    s = __shfl(s, 0);
    float inv = 1.f / (s + 1e-16f);
    for (int j = beg + lane; j < end; j += 64) alpha[j] *= inv;
}

// -------- aggregation: out[i,f] = bias[f] + sum_j alpha_j * t[src_j, f] ----
// wave per node, lane = float4 of features, 4-edge unroll for MLP

__global__ __launch_bounds__(256) void aggregate(const float* __restrict__ t,
                                                 const float* __restrict__ alpha,
                                                 const int* __restrict__ row_ptr,
                                                 const int* __restrict__ srcs,
                                                 const float* __restrict__ bias,
                                                 float* __restrict__ out, int N) {
    int wave = threadIdx.x >> 6;
    int lane = threadIdx.x & 63;
    int node = blockIdx.x * 4 + wave;
    if (node >= N) return;
    int beg = row_ptr[node], end = row_ptr[node + 1];
    const float4* t4 = (const float4*)t;
    float4 acc = ((const float4*)bias)[lane];
    int j = beg;
    for (; j + 4 <= end; j += 4) {
        int s0 = srcs[j + 0], s1 = srcs[j + 1], s2 = srcs[j + 2], s3 = srcs[j + 3];
        float a0 = alpha[j + 0], a1 = alpha[j + 1], a2 = alpha[j + 2], a3 = alpha[j + 3];
        float4 v0 = t4[s0 * 64 + lane];
        float4 v1 = t4[s1 * 64 + lane];
        float4 v2 = t4[s2 * 64 + lane];
        float4 v3 = t4[s3 * 64 + lane];
        acc.x = fmaf(a0, v0.x, acc.x); acc.y = fmaf(a0, v0.y, acc.y);
        acc.z = fmaf(a0, v0.z, acc.z); acc.w = fmaf(a0, v0.w, acc.w);
        acc.x = fmaf(a1, v1.x, acc.x); acc.y = fmaf(a1, v1.y, acc.y);
        acc.z = fmaf(a1, v1.z, acc.z); acc.w = fmaf(a1, v1.w, acc.w);
        acc.x = fmaf(a2, v2.x, acc.x); acc.y = fmaf(a2, v2.y, acc.y);
        acc.z = fmaf(a2, v2.z, acc.z); acc.w = fmaf(a2, v2.w, acc.w);
        acc.x = fmaf(a3, v3.x, acc.x); acc.y = fmaf(a3, v3.y, acc.y);
        acc.z = fmaf(a3, v3.z, acc.z); acc.w = fmaf(a3, v3.w, acc.w);
    }
    for (; j < end; ++j) {
        float a = alpha[j];
        float4 v = t4[srcs[j] * 64 + lane];
        acc.x = fmaf(a, v.x, acc.x); acc.y = fmaf(a, v.y, acc.y);
        acc.z = fmaf(a, v.z, acc.z); acc.w = fmaf(a, v.w, acc.w);
    }
    ((float4*)out)[node * 64 + lane] = acc;
}

// -------- logits: out[e] = dot(h[u], h[v]) ---------------------------------

__global__ __launch_bounds__(256) void edge_dot(const float* __restrict__ h,
                                                const int* __restrict__ ei,
                                                float* __restrict__ out, int EQ) {
    int w = threadIdx.x >> 6, lane = threadIdx.x & 63;
    int e = blockIdx.x * 4 + w;
    if (e >= EQ) return;
    int u = ei[e], v = ei[EQ + e];
    const float4* hu = (const float4*)(h + (size_t)u * FDIM);
    const float4* hv = (const float4*)(h + (size_t)v * FDIM);
    float4 a = hu[lane], b = hv[lane];
    float s = a.x * b.x + a.y * b.y + a.z * b.z + a.w * b.w;
    for (int o = 32; o; o >>= 1) s += __shfl_down(s, o);
    if (lane == 0) out[e] = s;
}

// ---------------------------------------------------------------------------

extern "C" void kernel_launch(void* const* d_in, const int* in_sizes, int n_in,
                              void* d_out, int out_size, void* d_ws, size_t ws_size,
                              hipStream_t stream) {
    const float* x       = (const float*)d_in[0];
    const int*   pos_ei  = (const int*)d_in[1];
    const int*   q_ei    = (const int*)d_in[2];
    const float* Win_W   = (const float*)d_in[3];
    const float* Win_b   = (const float*)d_in[4];
    const float* W1      = (const float*)d_in[5];
    const float* a1_src  = (const float*)d_in[6];
    const float* a1_dst  = (const float*)d_in[7];
    const float* b1      = (const float*)d_in[8];
    const float* W2      = (const float*)d_in[9];
    const float* a2_src  = (const float*)d_in[10];
    const float* a2_dst  = (const float*)d_in[11];
    const float* b2      = (const float*)d_in[12];
    float* logits = (float*)d_out;

    const int N = in_sizes[0] / FDIM;         // 10000
    const int E_pos = in_sizes[1] / 2;        // 320000
    const int EQ = in_sizes[2] / 2;           // 100000
    const int E_tot = E_pos + N;              // 330000

    // workspace carve-up (floats, then ints)
    float* h    = (float*)d_ws;               // N*FDIM
    float* t    = h + (size_t)N * FDIM;       // N*FDIM
    float* o2   = t + (size_t)N * FDIM;       // N*FDIM
    float* al_s = o2 + (size_t)N * FDIM;      // N
    float* al_d = al_s + N;                   // N
    float* alpha = al_d + N;                  // E_tot
    int* row_ptr = (int*)(alpha + E_tot);     // N+1
    int* fill    = row_ptr + (N + 1);         // N
    int* srcs    = fill + N;                  // E_tot
    int* cnt     = srcs + E_tot;              // N

    // ---- CSR build ----
    hipMemsetAsync(cnt, 0, (size_t)N * sizeof(int), stream);
    {
        int nb = (E_tot + 255) / 256;
        hist_dst<<<nb, 256, 0, stream>>>(pos_ei, cnt, E_pos, E_tot);
    }
    scan10k<<<1, 1024, 0, stream>>>(cnt, row_ptr, fill, N);
    {
        int nb = (E_tot + 255) / 256;
        scatter_edges<<<nb, 256, 0, stream>>>(pos_ei, fill, srcs, E_pos, E_tot);
    }

    dim3 ggrid((N + 63) / 64, FDIM / 64);
    int nblk4 = (N + 3) / 4;

    // ---- input weighting: h = x @ Win_W + Win_b ----
    gemm256<<<ggrid, 256, 0, stream>>>(x, Win_W, Win_b, h, N, 1);

    // ---- GAT layer 1: h -> o2 ----
    gemm256<<<ggrid, 256, 0, stream>>>(h, W1, nullptr, t, N, 0);
    attn_logits<<<nblk4, 256, 0, stream>>>(t, a1_src, a1_dst, al_s, al_d, N);
    edge_softmax<<<nblk4, 256, 0, stream>>>(al_s, al_d, row_ptr, srcs, alpha, N);
    aggregate<<<nblk4, 256, 0, stream>>>(t, alpha, row_ptr, srcs, b1, o2, N);

    // ---- GAT layer 2: o2 -> h ----
    gemm256<<<ggrid, 256, 0, stream>>>(o2, W2, nullptr, t, N, 0);
    attn_logits<<<nblk4, 256, 0, stream>>>(t, a2_src, a2_dst, al_s, al_d, N);
    edge_softmax<<<nblk4, 256, 0, stream>>>(al_s, al_d, row_ptr, srcs, alpha, N);
    aggregate<<<nblk4, 256, 0, stream>>>(t, alpha, row_ptr, srcs, b2, h, N);

    // ---- logits ----
    edge_dot<<<(EQ + 3) / 4, 256, 0, stream>>>(h, q_ei, logits, EQ);
}

// Round 3
// 289.243 us; speedup vs baseline: 1.4005x; 1.1645x over previous
//
#include <hip/hip_runtime.h>
#include <math.h>

#define FDIM 256
#define NEG_SLOPE 0.2f

typedef _Float16 half4v __attribute__((ext_vector_type(4)));
typedef _Float16 half8v __attribute__((ext_vector_type(8)));
typedef float f32x4 __attribute__((ext_vector_type(4)));

// ---------------- CSR build ----------------

__global__ void hist_dst(const int* __restrict__ pos_ei, int* __restrict__ cnt,
                         int E_pos, int E_tot) {
    int e = blockIdx.x * blockDim.x + threadIdx.x;
    if (e < E_tot) {
        int d = (e < E_pos) ? pos_ei[E_pos + e] : (e - E_pos);
        atomicAdd(&cnt[d], 1);
    }
}

__global__ __launch_bounds__(1024) void scan10k(const int* __restrict__ cnt,
                                                int* __restrict__ row_ptr,
                                                int* __restrict__ fill, int N) {
    const int CH = 10;
    __shared__ int sums[1024];
    int tid = threadIdx.x;
    int base = tid * CH;
    int vals[CH];
    int s = 0;
#pragma unroll
    for (int i = 0; i < CH; ++i) {
        int idx = base + i;
        int v = (idx < N) ? cnt[idx] : 0;
        vals[i] = s;
        s += v;
    }
    sums[tid] = s;
    __syncthreads();
    for (int off = 1; off < 1024; off <<= 1) {
        int v = (tid >= off) ? sums[tid - off] : 0;
        __syncthreads();
        sums[tid] += v;
        __syncthreads();
    }
    int toff = (tid == 0) ? 0 : sums[tid - 1];
#pragma unroll
    for (int i = 0; i < CH; ++i) {
        int idx = base + i;
        if (idx < N) {
            int rp = toff + vals[i];
            row_ptr[idx] = rp;
            fill[idx] = rp;
        }
    }
    if (tid == 0) row_ptr[N] = sums[1023];
}

__global__ void scatter_edges(const int* __restrict__ pos_ei, int* __restrict__ fill,
                              int* __restrict__ srcs, int E_pos, int E_tot) {
    int e = blockIdx.x * blockDim.x + threadIdx.x;
    if (e < E_tot) {
        int s, d;
        if (e < E_pos) { s = pos_ei[e]; d = pos_ei[E_pos + e]; }
        else           { s = e - E_pos; d = s; }
        int pos = atomicAdd(&fill[d], 1);
        srcs[pos] = s;
    }
}

// ------- weight prep: W[k][n] fp32 -> Wt_hi/Wt_lo[n][k] f16 (split) --------

__global__ __launch_bounds__(256) void prep_weights(const float* __restrict__ W0,
                                                    const float* __restrict__ W1,
                                                    const float* __restrict__ W2,
                                                    _Float16* __restrict__ Wt_hi,
                                                    _Float16* __restrict__ Wt_lo) {
    int n = blockIdx.x;    // 0..255
    int mat = blockIdx.y;  // 0..2
    const float* W = (mat == 0) ? W0 : (mat == 1) ? W1 : W2;
    int k = threadIdx.x;
    float v = W[k * FDIM + n];
    _Float16 hi = (_Float16)v;
    _Float16 lo = (_Float16)(v - (float)hi);
    size_t o = (size_t)mat * FDIM * FDIM + (size_t)n * FDIM + k;
    Wt_hi[o] = hi;
    Wt_lo[o] = lo;
}

// ------- split-f16 MFMA GEMM: C[M,256] = A[M,256] @ B[256,256] -------------
// optional bias add, optional fused attention projections (atomic into al_s/al_d)

__global__ __launch_bounds__(256) void gemm_mfma(
        const float* __restrict__ A, const _Float16* __restrict__ Bt_hi,
        const _Float16* __restrict__ Bt_lo, const float* __restrict__ bias,
        const float* __restrict__ a_src, const float* __restrict__ a_dst,
        float* __restrict__ C, float* __restrict__ al_s, float* __restrict__ al_d,
        int M) {
    __shared__ _Float16 As_hi[64][72];
    __shared__ _Float16 As_lo[64][72];
    __shared__ _Float16 Bs_hi[64][72];
    __shared__ _Float16 Bs_lo[64][72];
    int tid = threadIdx.x;
    int lane = tid & 63, w = tid >> 6;
    int wm = w >> 1, wn = w & 1;
    int quad = lane >> 4, l16 = lane & 15;
    int mBase = blockIdx.x * 64, nBase = blockIdx.y * 64;
    f32x4 acc[2][2] = {};

    for (int k0 = 0; k0 < FDIM; k0 += 64) {
        __syncthreads();  // prev-iter LDS reads done before overwrite
#pragma unroll
        for (int i = 0; i < 4; ++i) {
            int f = tid + i * 256;            // 64 rows x 16 float4
            int m = f >> 4, kc = (f & 15) << 2;
            int row = mBase + m;
            float4 a = make_float4(0.f, 0.f, 0.f, 0.f);
            if (row < M) a = *(const float4*)(A + (size_t)row * FDIM + k0 + kc);
            _Float16 hx = (_Float16)a.x, hy = (_Float16)a.y;
            _Float16 hz = (_Float16)a.z, hw = (_Float16)a.w;
            half4v hi = {hx, hy, hz, hw};
            half4v lo = {(_Float16)(a.x - (float)hx), (_Float16)(a.y - (float)hy),
                         (_Float16)(a.z - (float)hz), (_Float16)(a.w - (float)hw)};
            *(half4v*)&As_hi[m][kc] = hi;
            *(half4v*)&As_lo[m][kc] = lo;
        }
#pragma unroll
        for (int i = 0; i < 2; ++i) {
            int g = tid + i * 256;            // 64 rows x 8 half8
            int n = g >> 3, gk = (g & 7) << 3;
            size_t off = (size_t)(nBase + n) * FDIM + k0 + gk;
            *(half8v*)&Bs_hi[n][gk] = *(const half8v*)(Bt_hi + off);
            *(half8v*)&Bs_lo[n][gk] = *(const half8v*)(Bt_lo + off);
        }
        __syncthreads();
#pragma unroll
        for (int ks = 0; ks < 2; ++ks) {
            int kcol = ks * 32 + quad * 8;
            half8v aHi[2], aLo[2], bHi[2], bLo[2];
#pragma unroll
            for (int mt = 0; mt < 2; ++mt) {
                int r = wm * 32 + mt * 16 + l16;
                aHi[mt] = *(const half8v*)&As_hi[r][kcol];
                aLo[mt] = *(const half8v*)&As_lo[r][kcol];
            }
#pragma unroll
            for (int nt = 0; nt < 2; ++nt) {
                int c = wn * 32 + nt * 16 + l16;
                bHi[nt] = *(const half8v*)&Bs_hi[c][kcol];
                bLo[nt] = *(const half8v*)&Bs_lo[c][kcol];
            }
#pragma unroll
            for (int mt = 0; mt < 2; ++mt)
#pragma unroll
                for (int nt = 0; nt < 2; ++nt) {
                    acc[mt][nt] = __builtin_amdgcn_mfma_f32_16x16x32_f16(
                        aHi[mt], bHi[nt], acc[mt][nt], 0, 0, 0);
                    acc[mt][nt] = __builtin_amdgcn_mfma_f32_16x16x32_f16(
                        aHi[mt], bLo[nt], acc[mt][nt], 0, 0, 0);
                    acc[mt][nt] = __builtin_amdgcn_mfma_f32_16x16x32_f16(
                        aLo[mt], bHi[nt], acc[mt][nt], 0, 0, 0);
                }
        }
    }

    // epilogue: C write (+bias), optional fused attn projections
    bool do_attn = (a_src != nullptr);
    int col0 = nBase + wn * 32 + l16;
    int col1 = col0 + 16;
    float as0 = 0.f, as1 = 0.f, ad0 = 0.f, ad1 = 0.f, b0 = 0.f, b1v = 0.f;
    if (do_attn) { as0 = a_src[col0]; as1 = a_src[col1]; ad0 = a_dst[col0]; ad1 = a_dst[col1]; }
    if (bias) { b0 = bias[col0]; b1v = bias[col1]; }
#pragma unroll
    for (int mt = 0; mt < 2; ++mt) {
#pragma unroll
        for (int r = 0; r < 4; ++r) {
            int row = mBase + wm * 32 + mt * 16 + quad * 4 + r;
            if (row < M) {
                C[(size_t)row * FDIM + col0] = acc[mt][0][r] + b0;
                C[(size_t)row * FDIM + col1] = acc[mt][1][r] + b1v;
            }
            if (do_attn) {
                float ps = acc[mt][0][r] * as0 + acc[mt][1][r] * as1;
                float pd = acc[mt][0][r] * ad0 + acc[mt][1][r] * ad1;
#pragma unroll
                for (int off = 8; off; off >>= 1) {
                    ps += __shfl_xor(ps, off);
                    pd += __shfl_xor(pd, off);
                }
                if (l16 == 0 && row < M) {
                    atomicAdd(&al_s[row], ps);
                    atomicAdd(&al_d[row], pd);
                }
            }
        }
    }
}

// ------- fused edge-softmax + aggregation (wave per node) ------------------

__global__ __launch_bounds__(256) void softagg(
        const float* __restrict__ t, const float* __restrict__ al_s,
        const float* __restrict__ al_d, const int* __restrict__ row_ptr,
        const int* __restrict__ srcs, const float* __restrict__ bias,
        float* __restrict__ exbuf, float* __restrict__ out, int N) {
    int wave = threadIdx.x >> 6, lane = threadIdx.x & 63;
    int node = blockIdx.x * 4 + wave;
    bool valid = node < N;
    int beg = 0, end = 0;
    float inv = 0.f;
    if (valid) {
        beg = row_ptr[node];
        end = row_ptr[node + 1];
        float ad = al_d[node];
        float m = -INFINITY;
        for (int j = beg + lane; j < end; j += 64) {
            float e = al_s[srcs[j]] + ad;
            e = (e > 0.f) ? e : NEG_SLOPE * e;
            m = fmaxf(m, e);
        }
#pragma unroll
        for (int o = 32; o; o >>= 1) m = fmaxf(m, __shfl_xor(m, o));
        float s = 0.f;
        for (int j = beg + lane; j < end; j += 64) {
            float e = al_s[srcs[j]] + ad;
            e = (e > 0.f) ? e : NEG_SLOPE * e;
            float ex = __expf(e - m);
            exbuf[j] = ex;
            s += ex;
        }
#pragma unroll
        for (int o = 32; o; o >>= 1) s += __shfl_xor(s, o);
        inv = 1.f / (s + 1e-16f);
    }
    __syncthreads();  // exbuf cross-lane visibility
    if (!valid) return;
    const float4* t4 = (const float4*)t;
    float4 acc = make_float4(0.f, 0.f, 0.f, 0.f);
    int j = beg;
    for (; j + 4 <= end; j += 4) {
        int s0 = srcs[j + 0], s1 = srcs[j + 1], s2 = srcs[j + 2], s3 = srcs[j + 3];
        float a0 = exbuf[j + 0], a1 = exbuf[j + 1], a2 = exbuf[j + 2], a3 = exbuf[j + 3];
        float4 v0 = t4[s0 * 64 + lane];
        float4 v1 = t4[s1 * 64 + lane];
        float4 v2 = t4[s2 * 64 + lane];
        float4 v3 = t4[s3 * 64 + lane];
        acc.x = fmaf(a0, v0.x, acc.x); acc.y = fmaf(a0, v0.y, acc.y);
        acc.z = fmaf(a0, v0.z, acc.z); acc.w = fmaf(a0, v0.w, acc.w);
        acc.x = fmaf(a1, v1.x, acc.x); acc.y = fmaf(a1, v1.y, acc.y);
        acc.z = fmaf(a1, v1.z, acc.z); acc.w = fmaf(a1, v1.w, acc.w);
        acc.x = fmaf(a2, v2.x, acc.x); acc.y = fmaf(a2, v2.y, acc.y);
        acc.z = fmaf(a2, v2.z, acc.z); acc.w = fmaf(a2, v2.w, acc.w);
        acc.x = fmaf(a3, v3.x, acc.x); acc.y = fmaf(a3, v3.y, acc.y);
        acc.z = fmaf(a3, v3.z, acc.z); acc.w = fmaf(a3, v3.w, acc.w);
    }
    for (; j < end; ++j) {
        float a = exbuf[j];
        float4 v = t4[srcs[j] * 64 + lane];
        acc.x = fmaf(a, v.x, acc.x); acc.y = fmaf(a, v.y, acc.y);
        acc.z = fmaf(a, v.z, acc.z); acc.w = fmaf(a, v.w, acc.w);
    }
    float4 bv = ((const float4*)bias)[lane];
    float4 o;
    o.x = fmaf(acc.x, inv, bv.x);
    o.y = fmaf(acc.y, inv, bv.y);
    o.z = fmaf(acc.z, inv, bv.z);
    o.w = fmaf(acc.w, inv, bv.w);
    ((float4*)out)[node * 64 + lane] = o;
}

// -------- logits: out[e] = dot(h[u], h[v]) ---------------------------------

__global__ __launch_bounds__(256) void edge_dot(const float* __restrict__ h,
                                                const int* __restrict__ ei,
                                                float* __restrict__ out, int EQ) {
    int w = threadIdx.x >> 6, lane = threadIdx.x & 63;
    int e = blockIdx.x * 4 + w;
    if (e >= EQ) return;
    int u = ei[e], v = ei[EQ + e];
    const float4* hu = (const float4*)(h + (size_t)u * FDIM);
    const float4* hv = (const float4*)(h + (size_t)v * FDIM);
    float4 a = hu[lane], b = hv[lane];
    float s = a.x * b.x + a.y * b.y + a.z * b.z + a.w * b.w;
#pragma unroll
    for (int o = 32; o; o >>= 1) s += __shfl_down(s, o);
    if (lane == 0) out[e] = s;
}

// ---------------------------------------------------------------------------

extern "C" void kernel_launch(void* const* d_in, const int* in_sizes, int n_in,
                              void* d_out, int out_size, void* d_ws, size_t ws_size,
                              hipStream_t stream) {
    const float* x       = (const float*)d_in[0];
    const int*   pos_ei  = (const int*)d_in[1];
    const int*   q_ei    = (const int*)d_in[2];
    const float* Win_W   = (const float*)d_in[3];
    const float* Win_b   = (const float*)d_in[4];
    const float* W1      = (const float*)d_in[5];
    const float* a1_src  = (const float*)d_in[6];
    const float* a1_dst  = (const float*)d_in[7];
    const float* b1      = (const float*)d_in[8];
    const float* W2      = (const float*)d_in[9];
    const float* a2_src  = (const float*)d_in[10];
    const float* a2_dst  = (const float*)d_in[11];
    const float* b2      = (const float*)d_in[12];
    float* logits = (float*)d_out;

    const int N = in_sizes[0] / FDIM;   // 10000
    const int E_pos = in_sizes[1] / 2;  // 320000
    const int EQ = in_sizes[2] / 2;     // 100000
    const int E_tot = E_pos + N;        // 330000
    const int WMAT = FDIM * FDIM;       // 65536

    // workspace carve-up: f16 weight splits first (16B aligned), then floats, then ints
    _Float16* Wt_hi = (_Float16*)d_ws;          // 3*65536
    _Float16* Wt_lo = Wt_hi + 3 * WMAT;         // 3*65536
    float* h     = (float*)(Wt_lo + 3 * WMAT);  // N*FDIM
    float* t     = h + (size_t)N * FDIM;        // N*FDIM
    float* o2    = t + (size_t)N * FDIM;        // N*FDIM
    float* exbuf = o2 + (size_t)N * FDIM;       // E_tot
    float* al_s1 = exbuf + E_tot;               // N  -- zero region start
    float* al_d1 = al_s1 + N;                   // N
    float* al_s2 = al_d1 + N;                   // N
    float* al_d2 = al_s2 + N;                   // N
    int* cnt     = (int*)(al_d2 + N);           // N  -- zero region end
    int* row_ptr = cnt + N;                     // N+1
    int* fill    = row_ptr + (N + 1);           // N
    int* srcs    = fill + N;                    // E_tot

    // zero al_s1..al_d2 + cnt in one shot
    hipMemsetAsync(al_s1, 0, (size_t)(4 * N) * sizeof(float) + (size_t)N * sizeof(int), stream);

    // ---- CSR build ----
    {
        int nb = (E_tot + 255) / 256;
        hist_dst<<<nb, 256, 0, stream>>>(pos_ei, cnt, E_pos, E_tot);
        scan10k<<<1, 1024, 0, stream>>>(cnt, row_ptr, fill, N);
        scatter_edges<<<nb, 256, 0, stream>>>(pos_ei, fill, srcs, E_pos, E_tot);
    }

    // ---- weight prep ----
    prep_weights<<<dim3(FDIM, 3), 256, 0, stream>>>(Win_W, W1, W2, Wt_hi, Wt_lo);

    dim3 ggrid((N + 63) / 64, FDIM / 64);
    int nblk4 = (N + 3) / 4;

    // ---- input weighting: h = x @ Win_W + Win_b ----
    gemm_mfma<<<ggrid, 256, 0, stream>>>(x, Wt_hi, Wt_lo, Win_b,
                                         nullptr, nullptr, h, nullptr, nullptr, N);

    // ---- GAT layer 1 ----
    gemm_mfma<<<ggrid, 256, 0, stream>>>(h, Wt_hi + WMAT, Wt_lo + WMAT, nullptr,
                                         a1_src, a1_dst, t, al_s1, al_d1, N);
    softagg<<<nblk4, 256, 0, stream>>>(t, al_s1, al_d1, row_ptr, srcs, b1, exbuf, o2, N);

    // ---- GAT layer 2 ----
    gemm_mfma<<<ggrid, 256, 0, stream>>>(o2, Wt_hi + 2 * WMAT, Wt_lo + 2 * WMAT, nullptr,
                                         a2_src, a2_dst, t, al_s2, al_d2, N);
    softagg<<<nblk4, 256, 0, stream>>>(t, al_s2, al_d2, row_ptr, srcs, b2, exbuf, h, N);

    // ---- logits ----
    edge_dot<<<(EQ + 3) / 4, 256, 0, stream>>>(h, q_ei, logits, EQ);
}

// Round 4
// 239.342 us; speedup vs baseline: 1.6925x; 1.2085x over previous
//
#include <hip/hip_runtime.h>
#include <math.h>

#define FDIM 256
#define NEG_SLOPE 0.2f

typedef _Float16 half4v __attribute__((ext_vector_type(4)));
typedef _Float16 half8v __attribute__((ext_vector_type(8)));
typedef float f32x4 __attribute__((ext_vector_type(4)));

// ---------------- CSR build ----------------

__global__ void hist_dst(const int* __restrict__ pos_ei, int* __restrict__ cnt,
                         int E_pos, int E_tot) {
    int e = blockIdx.x * blockDim.x + threadIdx.x;
    if (e < E_tot) {
        int d = (e < E_pos) ? pos_ei[E_pos + e] : (e - E_pos);
        atomicAdd(&cnt[d], 1);
    }
}

__global__ __launch_bounds__(1024) void scan10k(const int* __restrict__ cnt,
                                                int* __restrict__ row_ptr,
                                                int* __restrict__ fill, int N) {
    const int CH = 10;
    __shared__ int sums[1024];
    int tid = threadIdx.x;
    int base = tid * CH;
    int vals[CH];
    int s = 0;
#pragma unroll
    for (int i = 0; i < CH; ++i) {
        int idx = base + i;
        int v = (idx < N) ? cnt[idx] : 0;
        vals[i] = s;
        s += v;
    }
    sums[tid] = s;
    __syncthreads();
    for (int off = 1; off < 1024; off <<= 1) {
        int v = (tid >= off) ? sums[tid - off] : 0;
        __syncthreads();
        sums[tid] += v;
        __syncthreads();
    }
    int toff = (tid == 0) ? 0 : sums[tid - 1];
#pragma unroll
    for (int i = 0; i < CH; ++i) {
        int idx = base + i;
        if (idx < N) {
            int rp = toff + vals[i];
            row_ptr[idx] = rp;
            fill[idx] = rp;
        }
    }
    if (tid == 0) row_ptr[N] = sums[1023];
}

__global__ void scatter_edges(const int* __restrict__ pos_ei, int* __restrict__ fill,
                              int* __restrict__ srcs, int E_pos, int E_tot) {
    int e = blockIdx.x * blockDim.x + threadIdx.x;
    if (e < E_tot) {
        int s, d;
        if (e < E_pos) { s = pos_ei[e]; d = pos_ei[E_pos + e]; }
        else           { s = e - E_pos; d = s; }
        int pos = atomicAdd(&fill[d], 1);
        srcs[pos] = s;
    }
}

// ------- weight prep: W[k][n] fp32 -> Wt_hi/Wt_lo[n][k] f16 (split) --------

__global__ __launch_bounds__(256) void prep_weights(const float* __restrict__ W0,
                                                    const float* __restrict__ W1,
                                                    const float* __restrict__ W2,
                                                    _Float16* __restrict__ Wt_hi,
                                                    _Float16* __restrict__ Wt_lo) {
    int n = blockIdx.x;
    int mat = blockIdx.y;
    const float* W = (mat == 0) ? W0 : (mat == 1) ? W1 : W2;
    int k = threadIdx.x;
    float v = W[k * FDIM + n];
    _Float16 hi = (_Float16)v;
    _Float16 lo = (_Float16)(v - (float)hi);
    size_t o = (size_t)mat * FDIM * FDIM + (size_t)n * FDIM + k;
    Wt_hi[o] = hi;
    Wt_lo[o] = lo;
}

// ------- split-f16 MFMA GEMM -----------------------------------------------
// MODE 0: A fp32 (inline split), C = split f16 (hi/lo) + bias   [Win]
// MODE 1: A pre-split f16 (hi/lo), C = f16, fused attn projections [W1,W2]

template <int MODE>
__global__ __launch_bounds__(256) void gemm_mfma(
        const float* __restrict__ A32,
        const _Float16* __restrict__ A_hi, const _Float16* __restrict__ A_lo,
        const _Float16* __restrict__ Bt_hi, const _Float16* __restrict__ Bt_lo,
        const float* __restrict__ bias,
        const float* __restrict__ a_src, const float* __restrict__ a_dst,
        float* __restrict__ al_s, float* __restrict__ al_d,
        _Float16* __restrict__ C_hi, _Float16* __restrict__ C_lo,
        int M) {
    __shared__ _Float16 As_hi[64][72];
    __shared__ _Float16 As_lo[64][72];
    __shared__ _Float16 Bs_hi[64][72];
    __shared__ _Float16 Bs_lo[64][72];
    int tid = threadIdx.x;
    int lane = tid & 63, w = tid >> 6;
    int wm = w >> 1, wn = w & 1;
    int quad = lane >> 4, l16 = lane & 15;
    int mBase = blockIdx.x * 64, nBase = blockIdx.y * 64;
    f32x4 acc[2][2] = {};

    for (int k0 = 0; k0 < FDIM; k0 += 64) {
        __syncthreads();
        if (MODE == 0) {
#pragma unroll
            for (int i = 0; i < 4; ++i) {
                int f = tid + i * 256;
                int m = f >> 4, kc = (f & 15) << 2;
                int row = mBase + m;
                float4 a = make_float4(0.f, 0.f, 0.f, 0.f);
                if (row < M) a = *(const float4*)(A32 + (size_t)row * FDIM + k0 + kc);
                _Float16 hx = (_Float16)a.x, hy = (_Float16)a.y;
                _Float16 hz = (_Float16)a.z, hw = (_Float16)a.w;
                half4v hi = {hx, hy, hz, hw};
                half4v lo = {(_Float16)(a.x - (float)hx), (_Float16)(a.y - (float)hy),
                             (_Float16)(a.z - (float)hz), (_Float16)(a.w - (float)hw)};
                *(half4v*)&As_hi[m][kc] = hi;
                *(half4v*)&As_lo[m][kc] = lo;
            }
        } else {
#pragma unroll
            for (int i = 0; i < 2; ++i) {
                int g = tid + i * 256;
                int m = g >> 3, gk = (g & 7) << 3;
                int row = mBase + m;
                half8v hi, lo;
                if (row < M) {
                    size_t off = (size_t)row * FDIM + k0 + gk;
                    hi = *(const half8v*)(A_hi + off);
                    lo = *(const half8v*)(A_lo + off);
                } else {
                    _Float16 z = (_Float16)0.f;
                    hi = (half8v){z, z, z, z, z, z, z, z};
                    lo = hi;
                }
                *(half8v*)&As_hi[m][gk] = hi;
                *(half8v*)&As_lo[m][gk] = lo;
            }
        }
#pragma unroll
        for (int i = 0; i < 2; ++i) {
            int g = tid + i * 256;
            int n = g >> 3, gk = (g & 7) << 3;
            size_t off = (size_t)(nBase + n) * FDIM + k0 + gk;
            *(half8v*)&Bs_hi[n][gk] = *(const half8v*)(Bt_hi + off);
            *(half8v*)&Bs_lo[n][gk] = *(const half8v*)(Bt_lo + off);
        }
        __syncthreads();
#pragma unroll
        for (int ks = 0; ks < 2; ++ks) {
            int kcol = ks * 32 + quad * 8;
            half8v aHi[2], aLo[2], bHi[2], bLo[2];
#pragma unroll
            for (int mt = 0; mt < 2; ++mt) {
                int r = wm * 32 + mt * 16 + l16;
                aHi[mt] = *(const half8v*)&As_hi[r][kcol];
                aLo[mt] = *(const half8v*)&As_lo[r][kcol];
            }
#pragma unroll
            for (int nt = 0; nt < 2; ++nt) {
                int c = wn * 32 + nt * 16 + l16;
                bHi[nt] = *(const half8v*)&Bs_hi[c][kcol];
                bLo[nt] = *(const half8v*)&Bs_lo[c][kcol];
            }
#pragma unroll
            for (int mt = 0; mt < 2; ++mt)
#pragma unroll
                for (int nt = 0; nt < 2; ++nt) {
                    acc[mt][nt] = __builtin_amdgcn_mfma_f32_16x16x32_f16(
                        aHi[mt], bHi[nt], acc[mt][nt], 0, 0, 0);
                    acc[mt][nt] = __builtin_amdgcn_mfma_f32_16x16x32_f16(
                        aHi[mt], bLo[nt], acc[mt][nt], 0, 0, 0);
                    acc[mt][nt] = __builtin_amdgcn_mfma_f32_16x16x32_f16(
                        aLo[mt], bHi[nt], acc[mt][nt], 0, 0, 0);
                }
        }
    }

    int col0 = nBase + wn * 32 + l16;
    int col1 = col0 + 16;
    if (MODE == 0) {
        float b0 = bias[col0], b1v = bias[col1];
#pragma unroll
        for (int mt = 0; mt < 2; ++mt) {
#pragma unroll
            for (int r = 0; r < 4; ++r) {
                int row = mBase + wm * 32 + mt * 16 + quad * 4 + r;
                if (row >= M) continue;
                float o0 = acc[mt][0][r] + b0;
                float o1 = acc[mt][1][r] + b1v;
                _Float16 h0 = (_Float16)o0, h1 = (_Float16)o1;
                size_t p0 = (size_t)row * FDIM + col0;
                size_t p1 = (size_t)row * FDIM + col1;
                C_hi[p0] = h0;              C_hi[p1] = h1;
                C_lo[p0] = (_Float16)(o0 - (float)h0);
                C_lo[p1] = (_Float16)(o1 - (float)h1);
            }
        }
    } else {
        float as0 = a_src[col0], as1 = a_src[col1];
        float ad0 = a_dst[col0], ad1 = a_dst[col1];
#pragma unroll
        for (int mt = 0; mt < 2; ++mt) {
#pragma unroll
            for (int r = 0; r < 4; ++r) {
                int row = mBase + wm * 32 + mt * 16 + quad * 4 + r;
                if (row < M) {
                    C_hi[(size_t)row * FDIM + col0] = (_Float16)acc[mt][0][r];
                    C_hi[(size_t)row * FDIM + col1] = (_Float16)acc[mt][1][r];
                }
                float ps = acc[mt][0][r] * as0 + acc[mt][1][r] * as1;
                float pd = acc[mt][0][r] * ad0 + acc[mt][1][r] * ad1;
#pragma unroll
                for (int off = 8; off; off >>= 1) {
                    ps += __shfl_xor(ps, off);
                    pd += __shfl_xor(pd, off);
                }
                if (l16 == 0 && row < M) {
                    atomicAdd(&al_s[row], ps);
                    atomicAdd(&al_d[row], pd);
                }
            }
        }
    }
}

// ------- fused edge-softmax + aggregation (wave per node, register-cached) -
// out: split f16 (out_hi/out_lo) if out32 == nullptr, else fp32

__global__ __launch_bounds__(256) void softagg(
        const _Float16* __restrict__ t, const float* __restrict__ al_s,
        const float* __restrict__ al_d, const int* __restrict__ row_ptr,
        const int* __restrict__ srcs, const float* __restrict__ bias,
        _Float16* __restrict__ out_hi, _Float16* __restrict__ out_lo,
        float* __restrict__ out32, int N) {
    int wave = threadIdx.x >> 6, lane = threadIdx.x & 63;
    int node = blockIdx.x * 4 + wave;
    if (node >= N) return;
    int beg = row_ptr[node], end = row_ptr[node + 1];
    int deg = end - beg;
    float ad = al_d[node];
    const _Float16* tb = t + (size_t)lane * 4;
    float4 acc = make_float4(0.f, 0.f, 0.f, 0.f);
    float ssum = 0.f;

    if (deg <= 256) {
        float e[4];
        int sj[4];
#pragma unroll
        for (int c = 0; c < 4; ++c) {
            e[c] = -INFINITY;
            sj[c] = 0;
            int j = beg + c * 64 + lane;
            if (j < end) {
                int s = srcs[j];
                sj[c] = s;
                float ee = al_s[s] + ad;
                e[c] = (ee > 0.f) ? ee : NEG_SLOPE * ee;
            }
        }
        float m = fmaxf(fmaxf(e[0], e[1]), fmaxf(e[2], e[3]));
#pragma unroll
        for (int o = 32; o; o >>= 1) m = fmaxf(m, __shfl_xor(m, o));
        float ex[4];
#pragma unroll
        for (int c = 0; c < 4; ++c) {
            ex[c] = (e[c] == -INFINITY) ? 0.f : __expf(e[c] - m);
            ssum += ex[c];
        }
#pragma unroll
        for (int c = 0; c < 4; ++c) {
            int jc = beg + c * 64;
            if (jc >= end) break;
            int cnt = min(64, end - jc);
            int jj = 0;
            for (; jj + 4 <= cnt; jj += 4) {
                float a0 = __shfl(ex[c], jj + 0), a1 = __shfl(ex[c], jj + 1);
                float a2 = __shfl(ex[c], jj + 2), a3 = __shfl(ex[c], jj + 3);
                int r0 = __shfl(sj[c], jj + 0), r1 = __shfl(sj[c], jj + 1);
                int r2 = __shfl(sj[c], jj + 2), r3 = __shfl(sj[c], jj + 3);
                half4v v0 = *(const half4v*)(tb + (size_t)r0 * FDIM);
                half4v v1 = *(const half4v*)(tb + (size_t)r1 * FDIM);
                half4v v2 = *(const half4v*)(tb + (size_t)r2 * FDIM);
                half4v v3 = *(const half4v*)(tb + (size_t)r3 * FDIM);
                acc.x = fmaf(a0, (float)v0.x, acc.x); acc.y = fmaf(a0, (float)v0.y, acc.y);
                acc.z = fmaf(a0, (float)v0.z, acc.z); acc.w = fmaf(a0, (float)v0.w, acc.w);
                acc.x = fmaf(a1, (float)v1.x, acc.x); acc.y = fmaf(a1, (float)v1.y, acc.y);
                acc.z = fmaf(a1, (float)v1.z, acc.z); acc.w = fmaf(a1, (float)v1.w, acc.w);
                acc.x = fmaf(a2, (float)v2.x, acc.x); acc.y = fmaf(a2, (float)v2.y, acc.y);
                acc.z = fmaf(a2, (float)v2.z, acc.z); acc.w = fmaf(a2, (float)v2.w, acc.w);
                acc.x = fmaf(a3, (float)v3.x, acc.x); acc.y = fmaf(a3, (float)v3.y, acc.y);
                acc.z = fmaf(a3, (float)v3.z, acc.z); acc.w = fmaf(a3, (float)v3.w, acc.w);
            }
            for (; jj < cnt; ++jj) {
                float a = __shfl(ex[c], jj);
                int r = __shfl(sj[c], jj);
                half4v v = *(const half4v*)(tb + (size_t)r * FDIM);
                acc.x = fmaf(a, (float)v.x, acc.x); acc.y = fmaf(a, (float)v.y, acc.y);
                acc.z = fmaf(a, (float)v.z, acc.z); acc.w = fmaf(a, (float)v.w, acc.w);
            }
        }
    } else {
        float m = -INFINITY;
        for (int j = beg + lane; j < end; j += 64) {
            float ee = al_s[srcs[j]] + ad;
            ee = (ee > 0.f) ? ee : NEG_SLOPE * ee;
            m = fmaxf(m, ee);
        }
#pragma unroll
        for (int o = 32; o; o >>= 1) m = fmaxf(m, __shfl_xor(m, o));
        for (int jc = beg; jc < end; jc += 64) {
            int j = jc + lane;
            float ex = 0.f;
            int sr = 0;
            if (j < end) {
                sr = srcs[j];
                float ee = al_s[sr] + ad;
                ee = (ee > 0.f) ? ee : NEG_SLOPE * ee;
                ex = __expf(ee - m);
                ssum += ex;
            }
            int cnt = min(64, end - jc);
            for (int jj = 0; jj < cnt; ++jj) {
                float a = __shfl(ex, jj);
                int r = __shfl(sr, jj);
                half4v v = *(const half4v*)(tb + (size_t)r * FDIM);
                acc.x = fmaf(a, (float)v.x, acc.x); acc.y = fmaf(a, (float)v.y, acc.y);
                acc.z = fmaf(a, (float)v.z, acc.z); acc.w = fmaf(a, (float)v.w, acc.w);
            }
        }
    }

#pragma unroll
    for (int o = 32; o; o >>= 1) ssum += __shfl_xor(ssum, o);
    float inv = 1.f / (ssum + 1e-16f);
    float4 bv = ((const float4*)bias)[lane];
    float ox = fmaf(acc.x, inv, bv.x);
    float oy = fmaf(acc.y, inv, bv.y);
    float oz = fmaf(acc.z, inv, bv.z);
    float ow = fmaf(acc.w, inv, bv.w);
    if (out32) {
        ((float4*)out32)[node * 64 + lane] = make_float4(ox, oy, oz, ow);
    } else {
        _Float16 hx = (_Float16)ox, hy = (_Float16)oy;
        _Float16 hz = (_Float16)oz, hw = (_Float16)ow;
        half4v hi = {hx, hy, hz, hw};
        half4v lo = {(_Float16)(ox - (float)hx), (_Float16)(oy - (float)hy),
                     (_Float16)(oz - (float)hz), (_Float16)(ow - (float)hw)};
        *(half4v*)(out_hi + (size_t)node * FDIM + lane * 4) = hi;
        *(half4v*)(out_lo + (size_t)node * FDIM + lane * 4) = lo;
    }
}

// -------- logits: out[e] = dot(h[u], h[v]) ---------------------------------

__global__ __launch_bounds__(256) void edge_dot(const float* __restrict__ h,
                                                const int* __restrict__ ei,
                                                float* __restrict__ out, int EQ) {
    int w = threadIdx.x >> 6, lane = threadIdx.x & 63;
    int e = blockIdx.x * 4 + w;
    if (e >= EQ) return;
    int u = ei[e], v = ei[EQ + e];
    const float4* hu = (const float4*)(h + (size_t)u * FDIM);
    const float4* hv = (const float4*)(h + (size_t)v * FDIM);
    float4 a = hu[lane], b = hv[lane];
    float s = a.x * b.x + a.y * b.y + a.z * b.z + a.w * b.w;
#pragma unroll
    for (int o = 32; o; o >>= 1) s += __shfl_down(s, o);
    if (lane == 0) out[e] = s;
}

// ---------------------------------------------------------------------------

extern "C" void kernel_launch(void* const* d_in, const int* in_sizes, int n_in,
                              void* d_out, int out_size, void* d_ws, size_t ws_size,
                              hipStream_t stream) {
    const float* x       = (const float*)d_in[0];
    const int*   pos_ei  = (const int*)d_in[1];
    const int*   q_ei    = (const int*)d_in[2];
    const float* Win_W   = (const float*)d_in[3];
    const float* Win_b   = (const float*)d_in[4];
    const float* W1      = (const float*)d_in[5];
    const float* a1_src  = (const float*)d_in[6];
    const float* a1_dst  = (const float*)d_in[7];
    const float* b1      = (const float*)d_in[8];
    const float* W2      = (const float*)d_in[9];
    const float* a2_src  = (const float*)d_in[10];
    const float* a2_dst  = (const float*)d_in[11];
    const float* b2      = (const float*)d_in[12];
    float* logits = (float*)d_out;

    const int N = in_sizes[0] / FDIM;   // 10000
    const int E_pos = in_sizes[1] / 2;  // 320000
    const int EQ = in_sizes[2] / 2;     // 100000
    const int E_tot = E_pos + N;        // 330000
    const size_t WMAT = (size_t)FDIM * FDIM;
    const size_t NF = (size_t)N * FDIM;

    // workspace carve-up: f16 arrays first, then fp32, then ints
    _Float16* Wt_hi = (_Float16*)d_ws;          // 3*WMAT
    _Float16* Wt_lo = Wt_hi + 3 * WMAT;         // 3*WMAT
    _Float16* h0_hi = Wt_lo + 3 * WMAT;         // NF (also o2_hi)
    _Float16* h0_lo = h0_hi + NF;               // NF (also o2_lo)
    _Float16* t_h   = h0_lo + NF;               // NF
    float* h32   = (float*)(t_h + NF);          // NF fp32
    float* al_s1 = h32 + NF;                    // N -- zero region start
    float* al_d1 = al_s1 + N;                   // N
    float* al_s2 = al_d1 + N;                   // N
    float* al_d2 = al_s2 + N;                   // N
    int* cnt     = (int*)(al_d2 + N);           // N -- zero region end
    int* row_ptr = cnt + N;                     // N+1
    int* fill    = row_ptr + (N + 1);           // N
    int* srcs    = fill + N;                    // E_tot

    hipMemsetAsync(al_s1, 0, (size_t)(4 * N) * sizeof(float) + (size_t)N * sizeof(int), stream);

    // ---- CSR build ----
    {
        int nb = (E_tot + 255) / 256;
        hist_dst<<<nb, 256, 0, stream>>>(pos_ei, cnt, E_pos, E_tot);
        scan10k<<<1, 1024, 0, stream>>>(cnt, row_ptr, fill, N);
        scatter_edges<<<nb, 256, 0, stream>>>(pos_ei, fill, srcs, E_pos, E_tot);
    }

    // ---- weight prep ----
    prep_weights<<<dim3(FDIM, 3), 256, 0, stream>>>(Win_W, W1, W2, Wt_hi, Wt_lo);

    dim3 ggrid((N + 63) / 64, FDIM / 64);
    int nblk4 = (N + 3) / 4;

    // ---- input weighting: h0(split) = x @ Win_W + Win_b ----
    gemm_mfma<0><<<ggrid, 256, 0, stream>>>(x, nullptr, nullptr, Wt_hi, Wt_lo, Win_b,
                                            nullptr, nullptr, nullptr, nullptr,
                                            h0_hi, h0_lo, N);

    // ---- GAT layer 1: t(f16) = h0 @ W1, attn -> al1; softagg -> o2(split) ----
    gemm_mfma<1><<<ggrid, 256, 0, stream>>>(nullptr, h0_hi, h0_lo,
                                            Wt_hi + WMAT, Wt_lo + WMAT, nullptr,
                                            a1_src, a1_dst, al_s1, al_d1,
                                            t_h, nullptr, N);
    softagg<<<nblk4, 256, 0, stream>>>(t_h, al_s1, al_d1, row_ptr, srcs, b1,
                                       h0_hi, h0_lo, nullptr, N);  // o2 aliases h0

    // ---- GAT layer 2: t(f16) = o2 @ W2, attn -> al2; softagg -> h32 ----
    gemm_mfma<1><<<ggrid, 256, 0, stream>>>(nullptr, h0_hi, h0_lo,
                                            Wt_hi + 2 * WMAT, Wt_lo + 2 * WMAT, nullptr,
                                            a2_src, a2_dst, al_s2, al_d2,
                                            t_h, nullptr, N);
    softagg<<<nblk4, 256, 0, stream>>>(t_h, al_s2, al_d2, row_ptr, srcs, b2,
                                       nullptr, nullptr, h32, N);

    // ---- logits ----
    edge_dot<<<(EQ + 3) / 4, 256, 0, stream>>>(h32, q_ei, logits, EQ);
}